// Round 1
// baseline (177.312 us; speedup 1.0000x reference)
//
#include <hip/hip_runtime.h>

typedef unsigned short u16;
typedef __attribute__((ext_vector_type(8))) short s16x8;
typedef __attribute__((ext_vector_type(4))) float f32x4;

#define MFMA16(a, b, c) __builtin_amdgcn_mfma_f32_16x16x32_bf16((a), (b), (c), 0, 0, 0)

// round-to-nearest-even f32 -> bf16 (as raw u16)
__device__ __forceinline__ u16 f2bf(float f) {
  unsigned u = __float_as_uint(f);
  u += 0x7fffu + ((u >> 16) & 1u);
  return (u16)(u >> 16);
}
__device__ __forceinline__ float bf2f(u16 h) { return __uint_as_float(((unsigned)h) << 16); }

// ---------------------------------------------------------------------------
// Kernel: transpose + split weights: W[K][N] f32 -> T{h,l}[N][K] bf16
// ---------------------------------------------------------------------------
__global__ __launch_bounds__(256) void wsplit_T(const float* __restrict__ W, int K, int N,
                                                u16* __restrict__ Th, u16* __restrict__ Tl) {
  int idx = blockIdx.x * 256 + threadIdx.x;
  int total = N * (K >> 3);
  if (idx >= total) return;
  int n = idx % N;
  int kc = idx / N;  // chunk of 8 k
  size_t ob = (size_t)n * K + (size_t)kc * 8;
  for (int i = 0; i < 8; ++i) {
    float f = W[(size_t)(kc * 8 + i) * N + n];
    u16 h = f2bf(f);
    Th[ob + i] = h;
    Tl[ob + i] = f2bf(f - bf2f(h));
  }
}

// ---------------------------------------------------------------------------
// GEMM1: qkv = X[8192][512] @ wqkv -> scattered epilogue to q/k/vT (bf16 hi/lo)
//   A: f32, converted+split during staging.  B: wqT{h,l}[1536][512].
//   q pre-scaled by D^-0.5 * log2(e)  (softmax later runs in exp2 domain)
// ---------------------------------------------------------------------------
__global__ __launch_bounds__(256) void gemm1_kernel(
    const float* __restrict__ X,
    const u16* __restrict__ Bht, const u16* __restrict__ Blt,
    u16* __restrict__ qh, u16* __restrict__ ql,
    u16* __restrict__ kh, u16* __restrict__ kl,
    u16* __restrict__ vth, u16* __restrict__ vtl) {
  __shared__ u16 Ah[128][64], Al[128][64], Bh[128][64], Bl[128][64];
  const int tid = threadIdx.x;
  const int wid = tid >> 6, lane = tid & 63;
  const int l15 = lane & 15, l4 = lane >> 4;
  const int row0 = blockIdx.x * 128;
  const int col0 = blockIdx.y * 128;
  const int wr = wid >> 1, wc = wid & 1;  // wave 2x2, each 64x64
  const f32x4 fz = {0.f, 0.f, 0.f, 0.f};
  f32x4 acc[4][4];
  for (int a = 0; a < 4; ++a)
    for (int b = 0; b < 4; ++b) acc[a][b] = fz;

  for (int k0 = 0; k0 < 512; k0 += 64) {
    __syncthreads();
    // stage B hi/lo (bf16), swizzled: LDS slot c holds global slot c^(r&7)
#pragma unroll
    for (int i = 0; i < 4; ++i) {
      int id = tid + i * 256;  // 0..1023 = 128 rows x 8 slots
      int r = id >> 3, c = id & 7;
      int gs = c ^ (r & 7);
      size_t go = (size_t)(col0 + r) * 512 + k0 + gs * 8;
      *(s16x8*)&Bh[r][c * 8] = *(const s16x8*)(Bht + go);
      *(s16x8*)&Bl[r][c * 8] = *(const s16x8*)(Blt + go);
    }
    // stage A: f32 -> (hi, lo) split, same swizzle
#pragma unroll
    for (int i = 0; i < 4; ++i) {
      int id = tid + i * 256;
      int r = id >> 3, c = id & 7;
      int gs = c ^ (r & 7);
      const float* src = X + (size_t)(row0 + r) * 512 + k0 + gs * 8;
      float4 f0 = *(const float4*)src;
      float4 f1 = *(const float4*)(src + 4);
      float fs[8] = {f0.x, f0.y, f0.z, f0.w, f1.x, f1.y, f1.z, f1.w};
      s16x8 hv, lv;
#pragma unroll
      for (int j = 0; j < 8; ++j) {
        u16 h = f2bf(fs[j]);
        hv[j] = (short)h;
        lv[j] = (short)f2bf(fs[j] - bf2f(h));
      }
      *(s16x8*)&Ah[r][c * 8] = hv;
      *(s16x8*)&Al[r][c * 8] = lv;
    }
    __syncthreads();
#pragma unroll
    for (int ks = 0; ks < 2; ++ks) {
      s16x8 afh[4], afl[4];
#pragma unroll
      for (int mi = 0; mi < 4; ++mi) {
        int r = wr * 64 + mi * 16 + l15;
        int sl = (ks * 4 + l4) ^ (r & 7);
        afh[mi] = *(const s16x8*)&Ah[r][sl * 8];
        afl[mi] = *(const s16x8*)&Al[r][sl * 8];
      }
#pragma unroll
      for (int nj = 0; nj < 4; ++nj) {
        int r = wc * 64 + nj * 16 + l15;
        int sl = (ks * 4 + l4) ^ (r & 7);
        s16x8 bfh = *(const s16x8*)&Bh[r][sl * 8];
        s16x8 bfl = *(const s16x8*)&Bl[r][sl * 8];
#pragma unroll
        for (int mi = 0; mi < 4; ++mi) {
          acc[mi][nj] = MFMA16(afh[mi], bfh, acc[mi][nj]);
          acc[mi][nj] = MFMA16(afl[mi], bfh, acc[mi][nj]);
          acc[mi][nj] = MFMA16(afh[mi], bfl, acc[mi][nj]);
        }
      }
    }
  }
  // epilogue: scatter to q (scaled), k, vT as bf16 hi/lo
  const float QS = 0.06375874f;  // D^-0.5 * log2(e)
#pragma unroll
  for (int mi = 0; mi < 4; ++mi)
#pragma unroll
    for (int nj = 0; nj < 4; ++nj)
#pragma unroll
      for (int rg = 0; rg < 4; ++rg) {
        float v = acc[mi][nj][rg];
        int r_g = row0 + wr * 64 + mi * 16 + l4 * 4 + rg;
        int c_g = col0 + wc * 64 + nj * 16 + l15;
        int b = r_g >> 11, s = r_g & 2047;
        int h = c_g / 192;
        int rem = c_g - h * 192;
        int t = rem >> 6, d = rem & 63;
        int bh_ = b * 8 + h;
        if (t == 0) {
          v *= QS;
          u16 hi = f2bf(v), lo = f2bf(v - bf2f(hi));
          size_t o = ((size_t)bh_ * 2048 + s) * 64 + d;
          qh[o] = hi; ql[o] = lo;
        } else if (t == 1) {
          u16 hi = f2bf(v), lo = f2bf(v - bf2f(hi));
          size_t o = ((size_t)bh_ * 2048 + s) * 64 + d;
          kh[o] = hi; kl[o] = lo;
        } else {
          u16 hi = f2bf(v), lo = f2bf(v - bf2f(hi));
          size_t o = ((size_t)bh_ * 64 + d) * 2048 + s;
          vth[o] = hi; vtl[o] = lo;
        }
      }
}

// ---------------------------------------------------------------------------
// Banded flash attention. Block = (b, h, qtile of 128). 4 waves x 32 q-rows.
// Scores already in log2-domain (q pre-scaled). Mask |i-j|>128 -> -1e9.
// ---------------------------------------------------------------------------
__global__ __launch_bounds__(256) void attn_kernel(
    const u16* __restrict__ qh, const u16* __restrict__ ql,
    const u16* __restrict__ kh, const u16* __restrict__ kl,
    const u16* __restrict__ vth, const u16* __restrict__ vtl,
    u16* __restrict__ aoh, u16* __restrict__ aol) {
  __shared__ u16 Ph[4][32][64], Pl[4][32][64];
  const int tid = threadIdx.x;
  const int w = tid >> 6, lane = tid & 63;
  const int l15 = lane & 15, l4 = lane >> 4;
  int bid = blockIdx.x;
  int qt = bid & 15, hh = (bid >> 4) & 7, b = bid >> 7;
  int bh_ = b * 8 + hh;
  const size_t base = (size_t)bh_ * 2048 * 64;
  int q0 = qt * 128 + w * 32;

  // Q fragments (A-operand): lane holds Q[row=l15][k=8*l4+j]
  s16x8 qfh[2][2], qfl[2][2];
#pragma unroll
  for (int mi = 0; mi < 2; ++mi)
#pragma unroll
    for (int ks = 0; ks < 2; ++ks) {
      size_t o = base + (size_t)(q0 + mi * 16 + l15) * 64 + ks * 32 + l4 * 8;
      qfh[mi][ks] = *(const s16x8*)(qh + o);
      qfl[mi][ks] = *(const s16x8*)(ql + o);
    }

  const f32x4 fz = {0.f, 0.f, 0.f, 0.f};
  f32x4 O[2][4];
  for (int mi = 0; mi < 2; ++mi)
    for (int nd = 0; nd < 4; ++nd) O[mi][nd] = fz;
  float m_r[2][4], l_r[2][4];
  for (int mi = 0; mi < 2; ++mi)
    for (int rg = 0; rg < 4; ++rg) { m_r[mi][rg] = -3.0e38f; l_r[mi][rg] = 0.f; }

  for (int dt = -1; dt <= 1; ++dt) {
    int kt = qt + dt;
    if (kt < 0 || kt > 15) continue;
    const bool domask = (dt != 0);
    for (int ch = 0; ch < 2; ++ch) {
      int kb = kt * 128 + ch * 64;  // 64 keys per chunk
      f32x4 S[2][4];
      for (int mi = 0; mi < 2; ++mi)
        for (int nj = 0; nj < 4; ++nj) S[mi][nj] = fz;
      // S = Q K^T  (3-term split)
#pragma unroll
      for (int nj = 0; nj < 4; ++nj)
#pragma unroll
        for (int ks = 0; ks < 2; ++ks) {
          size_t o = base + (size_t)(kb + nj * 16 + l15) * 64 + ks * 32 + l4 * 8;
          s16x8 kfh = *(const s16x8*)(kh + o);
          s16x8 kfl = *(const s16x8*)(kl + o);
#pragma unroll
          for (int mi = 0; mi < 2; ++mi) {
            S[mi][nj] = MFMA16(qfh[mi][ks], kfh, S[mi][nj]);
            S[mi][nj] = MFMA16(qfl[mi][ks], kfh, S[mi][nj]);
            S[mi][nj] = MFMA16(qfh[mi][ks], kfl, S[mi][nj]);
          }
        }
      if (domask) {
#pragma unroll
        for (int mi = 0; mi < 2; ++mi)
#pragma unroll
          for (int nj = 0; nj < 4; ++nj)
#pragma unroll
            for (int rg = 0; rg < 4; ++rg) {
              int row = q0 + mi * 16 + l4 * 4 + rg;
              int col = kb + nj * 16 + l15;
              int dd = col - row;
              if (dd > 128 || dd < -128) S[mi][nj][rg] = -1.0e9f;
            }
      }
      // online softmax update
#pragma unroll
      for (int mi = 0; mi < 2; ++mi)
#pragma unroll
        for (int rg = 0; rg < 4; ++rg) {
          float pm = fmaxf(fmaxf(S[mi][0][rg], S[mi][1][rg]), fmaxf(S[mi][2][rg], S[mi][3][rg]));
          pm = fmaxf(pm, __shfl_xor(pm, 1));
          pm = fmaxf(pm, __shfl_xor(pm, 2));
          pm = fmaxf(pm, __shfl_xor(pm, 4));
          pm = fmaxf(pm, __shfl_xor(pm, 8));
          float mnew = fmaxf(m_r[mi][rg], pm);
          float alpha = exp2f(m_r[mi][rg] - mnew);
          m_r[mi][rg] = mnew;
          l_r[mi][rg] *= alpha;
#pragma unroll
          for (int nd = 0; nd < 4; ++nd) O[mi][nd][rg] *= alpha;
        }
      // P = exp2(S - m): split to bf16 hi/lo, stash in per-wave swizzled LDS
#pragma unroll
      for (int mi = 0; mi < 2; ++mi) {
        float rs[4] = {0.f, 0.f, 0.f, 0.f};
#pragma unroll
        for (int nj = 0; nj < 4; ++nj)
#pragma unroll
          for (int rg = 0; rg < 4; ++rg) {
            float p = exp2f(S[mi][nj][rg] - m_r[mi][rg]);
            rs[rg] += p;
            u16 hi = f2bf(p), lo = f2bf(p - bf2f(hi));
            int row = mi * 16 + l4 * 4 + rg;
            int col = nj * 16 + l15;
            int e = (((col >> 3) ^ (row & 7)) << 3) + (col & 7);
            Ph[w][row][e] = hi;
            Pl[w][row][e] = lo;
          }
#pragma unroll
        for (int rg = 0; rg < 4; ++rg) {
          float s = rs[rg];
          s += __shfl_xor(s, 1);
          s += __shfl_xor(s, 2);
          s += __shfl_xor(s, 4);
          s += __shfl_xor(s, 8);
          l_r[mi][rg] += s;
        }
      }
      // O += P V   (3-term split; V read from vT[d][s] for contiguous-K b-frags)
#pragma unroll
      for (int ksp = 0; ksp < 2; ++ksp) {
        s16x8 pah[2], pal[2];
#pragma unroll
        for (int mi = 0; mi < 2; ++mi) {
          int row = mi * 16 + l15;
          int sl = (ksp * 4 + l4) ^ (row & 7);
          pah[mi] = *(const s16x8*)&Ph[w][row][sl * 8];
          pal[mi] = *(const s16x8*)&Pl[w][row][sl * 8];
        }
#pragma unroll
        for (int nd = 0; nd < 4; ++nd) {
          size_t o = base + (size_t)(nd * 16 + l15) * 2048 + kb + ksp * 32 + l4 * 8;
          s16x8 vh = *(const s16x8*)(vth + o);
          s16x8 vl = *(const s16x8*)(vtl + o);
#pragma unroll
          for (int mi = 0; mi < 2; ++mi) {
            O[mi][nd] = MFMA16(pah[mi], vh, O[mi][nd]);
            O[mi][nd] = MFMA16(pal[mi], vh, O[mi][nd]);
            O[mi][nd] = MFMA16(pah[mi], vl, O[mi][nd]);
          }
        }
      }
    }
  }
  // epilogue: O/l -> attn_out[b][s][h*64+d] bf16 hi/lo
#pragma unroll
  for (int mi = 0; mi < 2; ++mi)
#pragma unroll
    for (int rg = 0; rg < 4; ++rg) {
      float inv = 1.0f / l_r[mi][rg];
      int s_g = q0 + mi * 16 + l4 * 4 + rg;
#pragma unroll
      for (int nd = 0; nd < 4; ++nd) {
        float v = O[mi][nd][rg] * inv;
        int c_g = hh * 64 + nd * 16 + l15;
        size_t o = ((size_t)b * 2048 + s_g) * 512 + c_g;
        u16 hi = f2bf(v), lo = f2bf(v - bf2f(hi));
        aoh[o] = hi;
        aol[o] = lo;
      }
    }
}

// ---------------------------------------------------------------------------
// GEMM2: out[8192][512] f32 = attn (bf16 hi/lo) @ w_proj  (wpT hi/lo)
// ---------------------------------------------------------------------------
__global__ __launch_bounds__(256) void gemm2_kernel(
    const u16* __restrict__ Aht, const u16* __restrict__ Alt,
    const u16* __restrict__ Bht, const u16* __restrict__ Blt,
    float* __restrict__ OUT) {
  __shared__ u16 Ah[128][64], Al[128][64], Bh[128][64], Bl[128][64];
  const int tid = threadIdx.x;
  const int wid = tid >> 6, lane = tid & 63;
  const int l15 = lane & 15, l4 = lane >> 4;
  const int row0 = blockIdx.x * 128;
  const int col0 = blockIdx.y * 128;
  const int wr = wid >> 1, wc = wid & 1;
  const f32x4 fz = {0.f, 0.f, 0.f, 0.f};
  f32x4 acc[4][4];
  for (int a = 0; a < 4; ++a)
    for (int b = 0; b < 4; ++b) acc[a][b] = fz;

  for (int k0 = 0; k0 < 512; k0 += 64) {
    __syncthreads();
#pragma unroll
    for (int i = 0; i < 4; ++i) {
      int id = tid + i * 256;
      int r = id >> 3, c = id & 7;
      int gs = c ^ (r & 7);
      size_t ga = (size_t)(row0 + r) * 512 + k0 + gs * 8;
      size_t gb = (size_t)(col0 + r) * 512 + k0 + gs * 8;
      *(s16x8*)&Ah[r][c * 8] = *(const s16x8*)(Aht + ga);
      *(s16x8*)&Al[r][c * 8] = *(const s16x8*)(Alt + ga);
      *(s16x8*)&Bh[r][c * 8] = *(const s16x8*)(Bht + gb);
      *(s16x8*)&Bl[r][c * 8] = *(const s16x8*)(Blt + gb);
    }
    __syncthreads();
#pragma unroll
    for (int ks = 0; ks < 2; ++ks) {
      s16x8 afh[4], afl[4];
#pragma unroll
      for (int mi = 0; mi < 4; ++mi) {
        int r = wr * 64 + mi * 16 + l15;
        int sl = (ks * 4 + l4) ^ (r & 7);
        afh[mi] = *(const s16x8*)&Ah[r][sl * 8];
        afl[mi] = *(const s16x8*)&Al[r][sl * 8];
      }
#pragma unroll
      for (int nj = 0; nj < 4; ++nj) {
        int r = wc * 64 + nj * 16 + l15;
        int sl = (ks * 4 + l4) ^ (r & 7);
        s16x8 bfh = *(const s16x8*)&Bh[r][sl * 8];
        s16x8 bfl = *(const s16x8*)&Bl[r][sl * 8];
#pragma unroll
        for (int mi = 0; mi < 4; ++mi) {
          acc[mi][nj] = MFMA16(afh[mi], bfh, acc[mi][nj]);
          acc[mi][nj] = MFMA16(afl[mi], bfh, acc[mi][nj]);
          acc[mi][nj] = MFMA16(afh[mi], bfl, acc[mi][nj]);
        }
      }
    }
  }
#pragma unroll
  for (int mi = 0; mi < 4; ++mi)
#pragma unroll
    for (int nj = 0; nj < 4; ++nj)
#pragma unroll
      for (int rg = 0; rg < 4; ++rg) {
        int r_g = row0 + wr * 64 + mi * 16 + l4 * 4 + rg;
        int c_g = col0 + wc * 64 + nj * 16 + l15;
        OUT[(size_t)r_g * 512 + c_g] = acc[mi][nj][rg];
      }
}

// ---------------------------------------------------------------------------
extern "C" void kernel_launch(void* const* d_in, const int* in_sizes, int n_in,
                              void* d_out, int out_size, void* d_ws, size_t ws_size,
                              hipStream_t stream) {
  const float* x = (const float*)d_in[0];      // [4,2048,512]
  const float* wqkv = (const float*)d_in[1];   // [512,1536]
  const float* wproj = (const float*)d_in[2];  // [512,512]
  float* out = (float*)d_out;                  // [4,2048,512]

  char* ws = (char*)d_ws;
  size_t off = 0;
  auto alloc = [&](size_t bytes) {
    void* p = ws + off;
    off += (bytes + 255) & ~(size_t)255;
    return p;
  };
  const size_t E = (size_t)4 * 8 * 2048 * 64;  // 4.19M elems per tensor
  u16* qh  = (u16*)alloc(E * 2);
  u16* ql  = (u16*)alloc(E * 2);
  u16* kh  = (u16*)alloc(E * 2);
  u16* kl  = (u16*)alloc(E * 2);
  u16* vth = (u16*)alloc(E * 2);
  u16* vtl = (u16*)alloc(E * 2);
  u16* aoh = (u16*)alloc(E * 2);
  u16* aol = (u16*)alloc(E * 2);
  u16* wqTh = (u16*)alloc((size_t)1536 * 512 * 2);
  u16* wqTl = (u16*)alloc((size_t)1536 * 512 * 2);
  u16* wpTh = (u16*)alloc((size_t)512 * 512 * 2);
  u16* wpTl = (u16*)alloc((size_t)512 * 512 * 2);

  wsplit_T<<<dim3((1536 * 64 + 255) / 256), dim3(256), 0, stream>>>(wqkv, 512, 1536, wqTh, wqTl);
  wsplit_T<<<dim3((512 * 64 + 255) / 256), dim3(256), 0, stream>>>(wproj, 512, 512, wpTh, wpTl);
  gemm1_kernel<<<dim3(64, 12), dim3(256), 0, stream>>>(x, wqTh, wqTl, qh, ql, kh, kl, vth, vtl);
  attn_kernel<<<dim3(512), dim3(256), 0, stream>>>(qh, ql, kh, kl, vth, vtl, aoh, aol);
  gemm2_kernel<<<dim3(64, 4), dim3(256), 0, stream>>>(aoh, aol, wpTh, wpTl, out);
}